// Round 4
// baseline (474.355 us; speedup 1.0000x reference)
//
#include <hip/hip_runtime.h>

#define HID  24
#define TT   262
#define KOUT 256
#define BPB  8      // batch elements per block (one 32-lane group each)
#define PSTR 260    // padded p stride

typedef float v2f __attribute__((ext_vector_type(2)));

// acc = a*b + acc (packed fp32, guaranteed v_pk_fma_f32)
#define PKFMA(acc, a, b) asm("v_pk_fma_f32 %0, %1, %2, %0" : "+v"(acc) : "v"(a), "v"(b))
// d = a*b (packed)
#define PKMUL(d, a, b)   asm("v_pk_mul_f32 %0, %1, %2"     : "=v"(d)   : "v"(a), "v"(b))
// Opaque def: pins value in a VGPR (pair); cannot be rematerialized/sunk into loop.
#define OPAQUE(x)        asm volatile("" : "+v"(x))

__device__ __forceinline__ float sig2(float x){   // sigma from pre-scaled arg: 1/(1+2^x)
    return __builtin_amdgcn_rcpf(1.0f + __builtin_amdgcn_exp2f(x));
}

// One GRU direction for one batch element per 32-lane group.
// lane i (<24) owns hidden unit i; lanes 24..31 carry zero weights (h stays 0).
// Cross-lane h exchange via LDS is wave-synchronous (no barriers in scan loop).
template<bool FWD>
__device__ __forceinline__ void run_dir(
    const float* xrow,            // LDS: this batch element's x, (TT,2)
    float* hrow,                  // LDS: 32 floats, h state
    float* prow,                  // LDS: PSTR floats, per-t projection partials
    const float* __restrict__ w_ih, const float* __restrict__ w_hh,
    const float* __restrict__ b_ih, const float* __restrict__ b_hh,
    const float* __restrict__ w_out, int lane)
{
    const int   ii  = (lane < HID) ? lane : 0;
    const float msk = (lane < HID) ? 1.0f : 0.0f;

    // Pre-scales: r,z rows by -log2(e) -> sigma(a) = 1/(1+2^A).
    // n rows (both hh and ih parts) by 2*log2(e) -> tanh(y) = 1 - 2/(1+2^Y).
    const float SRZ = -1.4426950408889634f * msk;
    const float SN  =  2.8853900817779268f * msk;

    // --- weights in NAMED registers; OPAQUE blocks rematerialization ---
    const float4* r4 = reinterpret_cast<const float4*>(w_hh + ii * HID);
    const float4* z4 = reinterpret_cast<const float4*>(w_hh + (HID + ii) * HID);
    const float4* n4 = reinterpret_cast<const float4*>(w_hh + (2 * HID + ii) * HID);
    v2f wr0,wr1,wr2,wr3,wr4,wr5,wr6,wr7,wr8,wr9,wr10,wr11;
    v2f wz0,wz1,wz2,wz3,wz4,wz5,wz6,wz7,wz8,wz9,wz10,wz11;
    v2f wn0,wn1,wn2,wn3,wn4,wn5,wn6,wn7,wn8,wn9,wn10,wn11;
#define LDW(d0, d1, Q, S) { float4 q_ = (Q); d0 = v2f{q_.x*(S), q_.y*(S)}; d1 = v2f{q_.z*(S), q_.w*(S)}; OPAQUE(d0); OPAQUE(d1); }
    LDW(wr0, wr1, r4[0], SRZ) LDW(wr2, wr3, r4[1], SRZ) LDW(wr4, wr5, r4[2], SRZ)
    LDW(wr6, wr7, r4[3], SRZ) LDW(wr8, wr9, r4[4], SRZ) LDW(wr10,wr11,r4[5], SRZ)
    LDW(wz0, wz1, z4[0], SRZ) LDW(wz2, wz3, z4[1], SRZ) LDW(wz4, wz5, z4[2], SRZ)
    LDW(wz6, wz7, z4[3], SRZ) LDW(wz8, wz9, z4[4], SRZ) LDW(wz10,wz11,z4[5], SRZ)
    LDW(wn0, wn1, n4[0], SN ) LDW(wn2, wn3, n4[1], SN ) LDW(wn4, wn5, n4[2], SN )
    LDW(wn6, wn7, n4[3], SN ) LDW(wn8, wn9, n4[4], SN ) LDW(wn10,wn11,n4[5], SN )
#undef LDW

    v2f wxr = v2f{w_ih[2*ii] * SRZ,           w_ih[2*ii+1] * SRZ};
    v2f wxz = v2f{w_ih[2*(HID+ii)] * SRZ,     w_ih[2*(HID+ii)+1] * SRZ};
    v2f wxn = v2f{w_ih[2*(2*HID+ii)] * SN,    w_ih[2*(2*HID+ii)+1] * SN};
    float br  = (b_ih[ii]       + b_hh[ii])       * SRZ;
    float bz  = (b_ih[HID+ii]   + b_hh[HID+ii])   * SRZ;
    float bnh =  b_hh[2*HID+ii] * SN;
    float bni =  b_ih[2*HID+ii] * SN;
    float pw  =  w_out[(FWD ? 0 : HID) + ii] * msk;
    OPAQUE(wxr); OPAQUE(wxz); OPAQUE(wxn);
    OPAQUE(br);  OPAQUE(bz);  OPAQUE(bnh); OPAQUE(bni); OPAQUE(pw);

    float hself = 0.0f;
    hrow[lane] = 0.0f;
    asm volatile("" ::: "memory");

    const float4* h4 = reinterpret_cast<const float4*>(hrow);
    int t = FWD ? 0 : (TT - 1);
    const int steps = FWD ? KOUT : TT;   // fwd t>=256 never reaches the sliced output

    #pragma unroll 1
    for (int s = 0; s < steps; ++s){
        const v2f xv = *reinterpret_cast<const v2f*>(xrow + 2 * t);

        v2f ar, az, ai;
        PKMUL(ar, xv, wxr);
        PKMUL(az, xv, wxz);
        PKMUL(ai, xv, wxn);
        v2f an = v2f{bnh, 0.0f};

        float4 h; v2f h0, h1;
        h = h4[0]; h0 = v2f{h.x,h.y}; h1 = v2f{h.z,h.w};
        PKFMA(ar,h0,wr0); PKFMA(ar,h1,wr1); PKFMA(az,h0,wz0); PKFMA(az,h1,wz1); PKFMA(an,h0,wn0); PKFMA(an,h1,wn1);
        h = h4[1]; h0 = v2f{h.x,h.y}; h1 = v2f{h.z,h.w};
        PKFMA(ar,h0,wr2); PKFMA(ar,h1,wr3); PKFMA(az,h0,wz2); PKFMA(az,h1,wz3); PKFMA(an,h0,wn2); PKFMA(an,h1,wn3);
        h = h4[2]; h0 = v2f{h.x,h.y}; h1 = v2f{h.z,h.w};
        PKFMA(ar,h0,wr4); PKFMA(ar,h1,wr5); PKFMA(az,h0,wz4); PKFMA(az,h1,wz5); PKFMA(an,h0,wn4); PKFMA(an,h1,wn5);
        h = h4[3]; h0 = v2f{h.x,h.y}; h1 = v2f{h.z,h.w};
        PKFMA(ar,h0,wr6); PKFMA(ar,h1,wr7); PKFMA(az,h0,wz6); PKFMA(az,h1,wz7); PKFMA(an,h0,wn6); PKFMA(an,h1,wn7);
        h = h4[4]; h0 = v2f{h.x,h.y}; h1 = v2f{h.z,h.w};
        PKFMA(ar,h0,wr8); PKFMA(ar,h1,wr9); PKFMA(az,h0,wz8); PKFMA(az,h1,wz9); PKFMA(an,h0,wn8); PKFMA(an,h1,wn9);
        h = h4[5]; h0 = v2f{h.x,h.y}; h1 = v2f{h.z,h.w};
        PKFMA(ar,h0,wr10); PKFMA(ar,h1,wr11); PKFMA(az,h0,wz10); PKFMA(az,h1,wz11); PKFMA(an,h0,wn10); PKFMA(an,h1,wn11);

        float R  = ar.x + ar.y + br;
        float Z  = az.x + az.y + bz;
        float GN = an.x + an.y;          // b_hh_n folded into init
        float GI = ai.x + ai.y + bni;

        float r = sig2(R);
        float z = sig2(Z);
        float Y = fmaf(r, GN, GI);
        float n = fmaf(-2.0f, __builtin_amdgcn_rcpf(1.0f + __builtin_amdgcn_exp2f(Y)), 1.0f);
        float hnew = fmaf(z, hself - n, n);   // (1-z)*n + z*h
        hself = hnew;
        hrow[lane] = hnew;

        float pv = hnew * pw;
        pv += __shfl_xor(pv, 1);
        pv += __shfl_xor(pv, 2);
        pv += __shfl_xor(pv, 4);
        pv += __shfl_xor(pv, 8);
        pv += __shfl_xor(pv, 16);
        if (FWD){
            if (lane == 0) prow[t] = pv;
        } else {
            if (lane == 0 && t < KOUT) prow[t] += pv;
        }
        asm volatile("" ::: "memory");   // order hrow write vs next step's reads
        t += FWD ? 1 : -1;
    }
}

__global__
__attribute__((amdgpu_flat_work_group_size(256, 256)))
__attribute__((amdgpu_waves_per_eu(4, 4)))
void birnn_kernel(
    const float* __restrict__ x,
    const float* __restrict__ w_ih_f, const float* __restrict__ w_hh_f,
    const float* __restrict__ b_ih_f, const float* __restrict__ b_hh_f,
    const float* __restrict__ w_ih_b, const float* __restrict__ w_hh_b,
    const float* __restrict__ b_ih_b, const float* __restrict__ b_hh_b,
    const float* __restrict__ w_out,  const float* __restrict__ b_out,
    float* __restrict__ out)
{
    __shared__ __align__(16) float4 xs4[BPB * TT * 2 / 4];   // 16768 B staged x
    __shared__ __align__(16) float  hsm[BPB][32];            //  1024 B h state
    __shared__ float  psm[BPB][PSTR];                        //  8320 B projection partials

    const int tid  = threadIdx.x;
    const int g    = tid >> 5;
    const int lane = tid & 31;
    const int b0   = blockIdx.x * BPB;

    // stage this block's 8 batch rows of x (contiguous 4192 floats), coalesced
    const float4* xg = reinterpret_cast<const float4*>(x + (size_t)b0 * (TT * 2));
    for (int i = tid; i < BPB * TT * 2 / 4; i += 256) xs4[i] = xg[i];
    __syncthreads();

    const float* xrow = reinterpret_cast<const float*>(xs4) + g * (TT * 2);
    run_dir<true >(xrow, hsm[g], psm[g], w_ih_f, w_hh_f, b_ih_f, b_hh_f, w_out, lane);
    run_dir<false>(xrow, hsm[g], psm[g], w_ih_b, w_hh_b, b_ih_b, b_hh_b, w_out, lane);
    __syncthreads();

    const float bo = b_out[0];
    for (int i = tid; i < BPB * KOUT; i += 256){
        int bl = i >> 8, t = i & 255;
        out[(size_t)(b0 + bl) * KOUT + t] = psm[bl][t] + bo;
    }
}

extern "C" void kernel_launch(void* const* d_in, const int* in_sizes, int n_in,
                              void* d_out, int out_size, void* d_ws, size_t ws_size,
                              hipStream_t stream)
{
    const float* x      = (const float*)d_in[0];
    const float* w_ih_f = (const float*)d_in[1];
    const float* w_hh_f = (const float*)d_in[2];
    const float* b_ih_f = (const float*)d_in[3];
    const float* b_hh_f = (const float*)d_in[4];
    const float* w_ih_b = (const float*)d_in[5];
    const float* w_hh_b = (const float*)d_in[6];
    const float* b_ih_b = (const float*)d_in[7];
    const float* b_hh_b = (const float*)d_in[8];
    const float* w_out  = (const float*)d_in[9];
    const float* b_out  = (const float*)d_in[10];
    float* out = (float*)d_out;

    birnn_kernel<<<dim3(8192 / BPB), dim3(256), 0, stream>>>(
        x, w_ih_f, w_hh_f, b_ih_f, b_hh_f,
        w_ih_b, w_hh_b, b_ih_b, b_hh_b, w_out, b_out, out);
}

// Round 6
// 452.781 us; speedup vs baseline: 1.0476x; 1.0476x over previous
//
#include <hip/hip_runtime.h>

#define HID  24
#define TT   262
#define KOUT 256
#define BPB  8      // batch elements per block (one 32-lane group each)
#define PSTR 260    // padded p stride

typedef _Float16 h2 __attribute__((ext_vector_type(2)));

// f32 += dot2(2xf16, 2xf16) — VOP3P V_DOT2_F32_F16
#define DOT2(acc, a, b) asm("v_dot2_f32_f16 %0, %1, %2, %0" : "+v"(acc) : "v"(a), "v"(b))
// Opaque def: pins value in a VGPR, blocks rematerialization of its def chain.
#define OPAQUE(x)       asm volatile("" : "+v"(x))

__device__ __forceinline__ float sig2(float x){   // sigma of pre-scaled arg: 1/(1+2^x)
    return __builtin_amdgcn_rcpf(1.0f + __builtin_amdgcn_exp2f(x));
}
__device__ __forceinline__ h2 pk(float a, float b){   // RTN f32->f16 pack
    h2 r; r.x = (_Float16)a; r.y = (_Float16)b; return r;
}

// One GRU direction for one batch element per 32-lane group.
// lane i (<24) owns hidden unit i; lanes 24..31 carry zero weights (h stays 0).
// h lives in LDS as f16[32] per group; all cross-lane exchange is wave-synchronous.
template<bool FWD>
__device__ __forceinline__ void run_dir(
    const float* xrow,            // LDS: this batch element's x, (TT,2) f32
    uint* hrow,                   // LDS: 16 uints = 32 f16, h state
    float* prow,                  // LDS: PSTR floats, per-t projection partials
    const float* __restrict__ w_ih, const float* __restrict__ w_hh,
    const float* __restrict__ b_ih, const float* __restrict__ b_hh,
    const float* __restrict__ w_out, int lane)
{
    const int   ii  = (lane < HID) ? lane : 0;
    const float msk = (lane < HID) ? 1.0f : 0.0f;

    // Pre-scales: r,z rows by -log2(e) -> sigma(a) = 1/(1+2^A).
    // n rows (hh and ih parts) by 2*log2(e) -> tanh(y) = 1 - 2/(1+2^Y).
    const float SRZ = -1.4426950408889634f * msk;
    const float SN  =  2.8853900817779268f * msk;

    const float4* r4 = reinterpret_cast<const float4*>(w_hh + ii * HID);
    const float4* z4 = reinterpret_cast<const float4*>(w_hh + (HID + ii) * HID);
    const float4* n4 = reinterpret_cast<const float4*>(w_hh + (2 * HID + ii) * HID);

    // 36 packed-f16 weight registers (was 72 f32)
    h2 wr0,wr1,wr2,wr3,wr4,wr5,wr6,wr7,wr8,wr9,wr10,wr11;
    h2 wz0,wz1,wz2,wz3,wz4,wz5,wz6,wz7,wz8,wz9,wz10,wz11;
    h2 wn0,wn1,wn2,wn3,wn4,wn5,wn6,wn7,wn8,wn9,wn10,wn11;
#define LDW(d0, d1, Q, S) { float4 q_ = (Q); d0 = pk(q_.x*(S), q_.y*(S)); d1 = pk(q_.z*(S), q_.w*(S)); OPAQUE(d0); OPAQUE(d1); }
    LDW(wr0, wr1, r4[0], SRZ) LDW(wr2, wr3, r4[1], SRZ) LDW(wr4, wr5, r4[2], SRZ)
    LDW(wr6, wr7, r4[3], SRZ) LDW(wr8, wr9, r4[4], SRZ) LDW(wr10,wr11,r4[5], SRZ)
    LDW(wz0, wz1, z4[0], SRZ) LDW(wz2, wz3, z4[1], SRZ) LDW(wz4, wz5, z4[2], SRZ)
    LDW(wz6, wz7, z4[3], SRZ) LDW(wz8, wz9, z4[4], SRZ) LDW(wz10,wz11,z4[5], SRZ)
    LDW(wn0, wn1, n4[0], SN ) LDW(wn2, wn3, n4[1], SN ) LDW(wn4, wn5, n4[2], SN )
    LDW(wn6, wn7, n4[3], SN ) LDW(wn8, wn9, n4[4], SN ) LDW(wn10,wn11,n4[5], SN )
#undef LDW

    h2 wxr = pk(w_ih[2*ii] * SRZ,          w_ih[2*ii+1] * SRZ);
    h2 wxz = pk(w_ih[2*(HID+ii)] * SRZ,    w_ih[2*(HID+ii)+1] * SRZ);
    h2 wxn = pk(w_ih[2*(2*HID+ii)] * SN,   w_ih[2*(2*HID+ii)+1] * SN);
    float br  = (b_ih[ii]       + b_hh[ii])       * SRZ;
    float bz  = (b_ih[HID+ii]   + b_hh[HID+ii])   * SRZ;
    float bnh =  b_hh[2*HID+ii] * SN;
    float bni =  b_ih[2*HID+ii] * SN;
    float pw  =  w_out[(FWD ? 0 : HID) + ii] * msk;
    OPAQUE(wxr); OPAQUE(wxz); OPAQUE(wxn);

    float hself = 0.0f;
    reinterpret_cast<_Float16*>(hrow)[lane] = (_Float16)0.0f;  // zero whole 32-f16 row
    asm volatile("" ::: "memory");

    const uint4* h16 = reinterpret_cast<const uint4*>(hrow);
    int t = FWD ? 0 : (TT - 1);
    const int steps = FWD ? KOUT : TT;   // fwd t>=256 never reaches the sliced output

    #pragma unroll 1
    for (int s = 0; s < steps; ++s){
        const float2 xv = *reinterpret_cast<const float2*>(xrow + 2 * t);
        const h2 xp = __builtin_bit_cast(h2, __builtin_amdgcn_cvt_pkrtz(xv.x, xv.y));

        float ar = br, az = bz, an = bnh, ai = bni;
        uint4 q; h2 hp;
#define D3(u, WR, WZ, WN) { hp = __builtin_bit_cast(h2, (u)); DOT2(ar, hp, WR); DOT2(az, hp, WZ); DOT2(an, hp, WN); }
        q = h16[0];
        D3(q.x, wr0, wz0, wn0) D3(q.y, wr1, wz1, wn1) D3(q.z, wr2, wz2, wn2) D3(q.w, wr3, wz3, wn3)
        q = h16[1];
        D3(q.x, wr4, wz4, wn4) D3(q.y, wr5, wz5, wn5) D3(q.z, wr6, wz6, wn6) D3(q.w, wr7, wz7, wn7)
        q = h16[2];
        D3(q.x, wr8, wz8, wn8) D3(q.y, wr9, wz9, wn9) D3(q.z, wr10,wz10,wn10) D3(q.w, wr11,wz11,wn11)
#undef D3
        DOT2(ar, xp, wxr);
        DOT2(az, xp, wxz);
        DOT2(ai, xp, wxn);

        float r = sig2(ar);
        float z = sig2(az);
        float Y = fmaf(r, an, ai);
        float n = fmaf(-2.0f, __builtin_amdgcn_rcpf(1.0f + __builtin_amdgcn_exp2f(Y)), 1.0f);
        float hnew = fmaf(z, hself - n, n);   // (1-z)*n + z*h
        hself = hnew;
        reinterpret_cast<_Float16*>(hrow)[lane] = (_Float16)hnew;

        float pv = hnew * pw;
        pv += __shfl_xor(pv, 1);
        pv += __shfl_xor(pv, 2);
        pv += __shfl_xor(pv, 4);
        pv += __shfl_xor(pv, 8);
        pv += __shfl_xor(pv, 16);
        if (FWD){
            if (lane == 0) prow[t] = pv;
        } else {
            if (lane == 0 && t < KOUT) prow[t] += pv;
        }
        asm volatile("" ::: "memory");   // order hrow write vs next step's reads
        t += FWD ? 1 : -1;
    }
}

__global__
__attribute__((amdgpu_flat_work_group_size(256, 256)))
__attribute__((amdgpu_waves_per_eu(4, 4)))
void birnn_kernel(
    const float* __restrict__ x,
    const float* __restrict__ w_ih_f, const float* __restrict__ w_hh_f,
    const float* __restrict__ b_ih_f, const float* __restrict__ b_hh_f,
    const float* __restrict__ w_ih_b, const float* __restrict__ w_hh_b,
    const float* __restrict__ b_ih_b, const float* __restrict__ b_hh_b,
    const float* __restrict__ w_out,  const float* __restrict__ b_out,
    float* __restrict__ out)
{
    __shared__ __align__(16) float4 xs4[BPB * TT * 2 / 4];   // 16768 B staged x
    __shared__ __align__(16) uint   hsm[BPB][16];            //   512 B h state (f16)
    __shared__ float  psm[BPB][PSTR];                        //  8320 B projection partials

    const int tid  = threadIdx.x;
    const int g    = tid >> 5;
    const int lane = tid & 31;
    const int b0   = blockIdx.x * BPB;

    // stage this block's 8 batch rows of x (contiguous 4192 floats), coalesced
    const float4* xg = reinterpret_cast<const float4*>(x + (size_t)b0 * (TT * 2));
    for (int i = tid; i < BPB * TT * 2 / 4; i += 256) xs4[i] = xg[i];
    __syncthreads();

    const float* xrow = reinterpret_cast<const float*>(xs4) + g * (TT * 2);
    run_dir<true >(xrow, hsm[g], psm[g], w_ih_f, w_hh_f, b_ih_f, b_hh_f, w_out, lane);
    run_dir<false>(xrow, hsm[g], psm[g], w_ih_b, w_hh_b, b_ih_b, b_hh_b, w_out, lane);
    __syncthreads();

    const float bo = b_out[0];
    for (int i = tid; i < BPB * KOUT; i += 256){
        int bl = i >> 8, t = i & 255;
        out[(size_t)(b0 + bl) * KOUT + t] = psm[bl][t] + bo;
    }
}

extern "C" void kernel_launch(void* const* d_in, const int* in_sizes, int n_in,
                              void* d_out, int out_size, void* d_ws, size_t ws_size,
                              hipStream_t stream)
{
    const float* x      = (const float*)d_in[0];
    const float* w_ih_f = (const float*)d_in[1];
    const float* w_hh_f = (const float*)d_in[2];
    const float* b_ih_f = (const float*)d_in[3];
    const float* b_hh_f = (const float*)d_in[4];
    const float* w_ih_b = (const float*)d_in[5];
    const float* w_hh_b = (const float*)d_in[6];
    const float* b_ih_b = (const float*)d_in[7];
    const float* b_hh_b = (const float*)d_in[8];
    const float* w_out  = (const float*)d_in[9];
    const float* b_out  = (const float*)d_in[10];
    float* out = (float*)d_out;

    birnn_kernel<<<dim3(8192 / BPB), dim3(256), 0, stream>>>(
        x, w_ih_f, w_hh_f, b_ih_f, b_hh_f,
        w_ih_b, w_hh_b, b_ih_b, b_hh_b, w_out, b_out, out);
}

// Round 7
// 395.681 us; speedup vs baseline: 1.1988x; 1.1443x over previous
//
#include <hip/hip_runtime.h>

#define HID  24
#define TT   262
#define KOUT 256
#define BPB  8      // batch elements per block (one 32-lane group each)
#define PSTR 260    // padded p stride

typedef _Float16 h2 __attribute__((ext_vector_type(2)));

// f32 += dot2(2xf16, 2xf16) — VOP3P V_DOT2_F32_F16
#define DOT2(acc, a, b) asm("v_dot2_f32_f16 %0, %1, %2, %0" : "+v"(acc) : "v"(a), "v"(b))
// Opaque def: pins value in a VGPR, blocks rematerialization of its def chain.
#define OPAQUE(x)       asm volatile("" : "+v"(x))

__device__ __forceinline__ float sig2(float x){   // sigma of pre-scaled arg: 1/(1+2^x)
    return __builtin_amdgcn_rcpf(1.0f + __builtin_amdgcn_exp2f(x));
}
__device__ __forceinline__ h2 pk(float a, float b){   // RTN f32->f16 pack
    h2 r; r.x = (_Float16)a; r.y = (_Float16)b; return r;
}

// Sum within each 32-lane half of the wave using DPP (pure VALU, no LDS pipe).
// After row_shr 1/2/4/8 each 16-row's lane15/31/47/63 holds its row sum;
// row_bcast15 adds lane15->lanes16-31 and lane47->lanes48-63.
// Result: lane 31 = sum(lanes 0..31), lane 63 = sum(lanes 32..63).
__device__ __forceinline__ float dpp_sum32(float v){
    int x;
    x = __builtin_amdgcn_update_dpp(0, __builtin_bit_cast(int, v), 0x111, 0xf, 0xf, true); v += __builtin_bit_cast(float, x);
    x = __builtin_amdgcn_update_dpp(0, __builtin_bit_cast(int, v), 0x112, 0xf, 0xf, true); v += __builtin_bit_cast(float, x);
    x = __builtin_amdgcn_update_dpp(0, __builtin_bit_cast(int, v), 0x114, 0xf, 0xf, true); v += __builtin_bit_cast(float, x);
    x = __builtin_amdgcn_update_dpp(0, __builtin_bit_cast(int, v), 0x118, 0xf, 0xf, true); v += __builtin_bit_cast(float, x);
    x = __builtin_amdgcn_update_dpp(0, __builtin_bit_cast(int, v), 0x142, 0xf, 0xf, true); v += __builtin_bit_cast(float, x);
    return v;
}

// One GRU direction for one batch element per 32-lane group.
// lane i (<24) owns hidden unit i; lanes 24..31 carry zero weights (h stays 0).
// h lives in LDS as f16[32] per group; all cross-lane exchange is wave-synchronous.
template<bool FWD>
__device__ __forceinline__ void run_dir(
    const float* xrow,            // LDS: this batch element's x, (TT,2) f32
    uint* hrow,                   // LDS: 16 uints = 32 f16, h state
    float* prow,                  // LDS: PSTR floats, per-t projection partials
    const float* __restrict__ w_ih, const float* __restrict__ w_hh,
    const float* __restrict__ b_ih, const float* __restrict__ b_hh,
    const float* __restrict__ w_out, int lane)
{
    const int   ii  = (lane < HID) ? lane : 0;
    const float msk = (lane < HID) ? 1.0f : 0.0f;

    // Pre-scales: r,z rows by -log2(e) -> sigma(a) = 1/(1+2^A).
    // n rows (hh and ih parts) by 2*log2(e) -> tanh(y) = 1 - 2/(1+2^Y).
    const float SRZ = -1.4426950408889634f * msk;
    const float SN  =  2.8853900817779268f * msk;

    const float4* r4 = reinterpret_cast<const float4*>(w_hh + ii * HID);
    const float4* z4 = reinterpret_cast<const float4*>(w_hh + (HID + ii) * HID);
    const float4* n4 = reinterpret_cast<const float4*>(w_hh + (2 * HID + ii) * HID);

    // 36 packed-f16 weight registers
    h2 wr0,wr1,wr2,wr3,wr4,wr5,wr6,wr7,wr8,wr9,wr10,wr11;
    h2 wz0,wz1,wz2,wz3,wz4,wz5,wz6,wz7,wz8,wz9,wz10,wz11;
    h2 wn0,wn1,wn2,wn3,wn4,wn5,wn6,wn7,wn8,wn9,wn10,wn11;
#define LDW(d0, d1, Q, S) { float4 q_ = (Q); d0 = pk(q_.x*(S), q_.y*(S)); d1 = pk(q_.z*(S), q_.w*(S)); OPAQUE(d0); OPAQUE(d1); }
    LDW(wr0, wr1, r4[0], SRZ) LDW(wr2, wr3, r4[1], SRZ) LDW(wr4, wr5, r4[2], SRZ)
    LDW(wr6, wr7, r4[3], SRZ) LDW(wr8, wr9, r4[4], SRZ) LDW(wr10,wr11,r4[5], SRZ)
    LDW(wz0, wz1, z4[0], SRZ) LDW(wz2, wz3, z4[1], SRZ) LDW(wz4, wz5, z4[2], SRZ)
    LDW(wz6, wz7, z4[3], SRZ) LDW(wz8, wz9, z4[4], SRZ) LDW(wz10,wz11,z4[5], SRZ)
    LDW(wn0, wn1, n4[0], SN ) LDW(wn2, wn3, n4[1], SN ) LDW(wn4, wn5, n4[2], SN )
    LDW(wn6, wn7, n4[3], SN ) LDW(wn8, wn9, n4[4], SN ) LDW(wn10,wn11,n4[5], SN )
#undef LDW

    h2 wxr = pk(w_ih[2*ii] * SRZ,          w_ih[2*ii+1] * SRZ);
    h2 wxz = pk(w_ih[2*(HID+ii)] * SRZ,    w_ih[2*(HID+ii)+1] * SRZ);
    h2 wxn = pk(w_ih[2*(2*HID+ii)] * SN,   w_ih[2*(2*HID+ii)+1] * SN);
    float br  = (b_ih[ii]       + b_hh[ii])       * SRZ;
    float bz  = (b_ih[HID+ii]   + b_hh[HID+ii])   * SRZ;
    float bnh =  b_hh[2*HID+ii] * SN;
    float bni =  b_ih[2*HID+ii] * SN;
    float pw  =  w_out[(FWD ? 0 : HID) + ii] * msk;
    OPAQUE(wxr); OPAQUE(wxz); OPAQUE(wxn);

    float hself = 0.0f;
    reinterpret_cast<_Float16*>(hrow)[lane] = (_Float16)0.0f;  // zero whole 32-f16 row
    asm volatile("" ::: "memory");

    const uint4* h16 = reinterpret_cast<const uint4*>(hrow);
    int t = FWD ? 0 : (TT - 1);
    const int steps = FWD ? KOUT : TT;   // fwd t>=256 never reaches the sliced output

    #pragma unroll 1
    for (int s = 0; s < steps; ++s){
        const float2 xv = *reinterpret_cast<const float2*>(xrow + 2 * t);
        const h2 xp = __builtin_bit_cast(h2, __builtin_amdgcn_cvt_pkrtz(xv.x, xv.y));

        float ar = br, az = bz, an = bnh, ai = bni;
        uint4 q; h2 hp;
#define D3(u, WR, WZ, WN) { hp = __builtin_bit_cast(h2, (u)); DOT2(ar, hp, WR); DOT2(az, hp, WZ); DOT2(an, hp, WN); }
        q = h16[0];
        D3(q.x, wr0, wz0, wn0) D3(q.y, wr1, wz1, wn1) D3(q.z, wr2, wz2, wn2) D3(q.w, wr3, wz3, wn3)
        q = h16[1];
        D3(q.x, wr4, wz4, wn4) D3(q.y, wr5, wz5, wn5) D3(q.z, wr6, wz6, wn6) D3(q.w, wr7, wz7, wn7)
        q = h16[2];
        D3(q.x, wr8, wz8, wn8) D3(q.y, wr9, wz9, wn9) D3(q.z, wr10,wz10,wn10) D3(q.w, wr11,wz11,wn11)
#undef D3
        DOT2(ar, xp, wxr);
        DOT2(az, xp, wxz);
        DOT2(ai, xp, wxn);

        float r = sig2(ar);
        float z = sig2(az);
        float Y = fmaf(r, an, ai);
        float n = fmaf(-2.0f, __builtin_amdgcn_rcpf(1.0f + __builtin_amdgcn_exp2f(Y)), 1.0f);
        float hnew = fmaf(z, hself - n, n);   // (1-z)*n + z*h
        hself = hnew;
        reinterpret_cast<_Float16*>(hrow)[lane] = (_Float16)hnew;

        // output projection: VALU-only DPP reduction (no LDS pipe, no bpermute)
        float pv = dpp_sum32(hnew * pw);
        if (FWD){
            if (lane == 31) prow[t] = pv;
        } else {
            if (lane == 31 && t < KOUT) prow[t] += pv;
        }
        asm volatile("" ::: "memory");   // order hrow write vs next step's reads
        t += FWD ? 1 : -1;
    }
}

__global__
__attribute__((amdgpu_flat_work_group_size(256, 256)))
__attribute__((amdgpu_waves_per_eu(4, 4)))
void birnn_kernel(
    const float* __restrict__ x,
    const float* __restrict__ w_ih_f, const float* __restrict__ w_hh_f,
    const float* __restrict__ b_ih_f, const float* __restrict__ b_hh_f,
    const float* __restrict__ w_ih_b, const float* __restrict__ w_hh_b,
    const float* __restrict__ b_ih_b, const float* __restrict__ b_hh_b,
    const float* __restrict__ w_out,  const float* __restrict__ b_out,
    float* __restrict__ out)
{
    __shared__ __align__(16) float4 xs4[BPB * TT * 2 / 4];   // 16768 B staged x
    __shared__ __align__(16) uint   hsm[BPB][16];            //   512 B h state (f16)
    __shared__ float  psm[BPB][PSTR];                        //  8320 B projection partials

    const int tid  = threadIdx.x;
    const int g    = tid >> 5;
    const int lane = tid & 31;
    const int b0   = blockIdx.x * BPB;

    // stage this block's 8 batch rows of x (contiguous 4192 floats), coalesced
    const float4* xg = reinterpret_cast<const float4*>(x + (size_t)b0 * (TT * 2));
    for (int i = tid; i < BPB * TT * 2 / 4; i += 256) xs4[i] = xg[i];
    __syncthreads();

    const float* xrow = reinterpret_cast<const float*>(xs4) + g * (TT * 2);
    run_dir<true >(xrow, hsm[g], psm[g], w_ih_f, w_hh_f, b_ih_f, b_hh_f, w_out, lane);
    run_dir<false>(xrow, hsm[g], psm[g], w_ih_b, w_hh_b, b_ih_b, b_hh_b, w_out, lane);
    __syncthreads();

    const float bo = b_out[0];
    for (int i = tid; i < BPB * KOUT; i += 256){
        int bl = i >> 8, t = i & 255;
        out[(size_t)(b0 + bl) * KOUT + t] = psm[bl][t] + bo;
    }
}

extern "C" void kernel_launch(void* const* d_in, const int* in_sizes, int n_in,
                              void* d_out, int out_size, void* d_ws, size_t ws_size,
                              hipStream_t stream)
{
    const float* x      = (const float*)d_in[0];
    const float* w_ih_f = (const float*)d_in[1];
    const float* w_hh_f = (const float*)d_in[2];
    const float* b_ih_f = (const float*)d_in[3];
    const float* b_hh_f = (const float*)d_in[4];
    const float* w_ih_b = (const float*)d_in[5];
    const float* w_hh_b = (const float*)d_in[6];
    const float* b_ih_b = (const float*)d_in[7];
    const float* b_hh_b = (const float*)d_in[8];
    const float* w_out  = (const float*)d_in[9];
    const float* b_out  = (const float*)d_in[10];
    float* out = (float*)d_out;

    birnn_kernel<<<dim3(8192 / BPB), dim3(256), 0, stream>>>(
        x, w_ih_f, w_hh_f, b_ih_f, b_hh_f,
        w_ih_b, w_hh_b, b_ih_b, b_hh_b, w_out, b_out, out);
}

// Round 11
// 394.512 us; speedup vs baseline: 1.2024x; 1.0030x over previous
//
#include <hip/hip_runtime.h>

#define HID  24
#define TT   262
#define KOUT 256
#define BPB  8      // batch elements per block (one 32-lane group each)
#define PSTR 260    // padded p stride

typedef _Float16 h2 __attribute__((ext_vector_type(2)));

// f32 += dot2(2xf16, 2xf16) — VOP3P V_DOT2_F32_F16
#define DOT2(acc, a, b) asm("v_dot2_f32_f16 %0, %1, %2, %0" : "+v"(acc) : "v"(a), "v"(b))
// Opaque def: pins value in a VGPR, blocks rematerialization of its def chain.
#define OPAQUE(x)       asm volatile("" : "+v"(x))

// Hard-set the arch-VGPR allocation (the allocator otherwise picks 64 and
// shuffles the overflow through AGPR moves / remat every scan iteration).
#if defined(__has_attribute)
#if __has_attribute(amdgpu_num_vgpr)
#define NUMVGPR_ATTR __attribute__((amdgpu_num_vgpr(128)))
#else
#define NUMVGPR_ATTR
#endif
#else
#define NUMVGPR_ATTR
#endif

__device__ __forceinline__ float sig2(float x){   // sigma of pre-scaled arg: 1/(1+2^x)
    return __builtin_amdgcn_rcpf(1.0f + __builtin_amdgcn_exp2f(x));
}
__device__ __forceinline__ h2 pk(float a, float b){   // RTN f32->f16 pack
    h2 r; r.x = (_Float16)a; r.y = (_Float16)b; return r;
}

// Sum within each 32-lane half of the wave using DPP (pure VALU, no LDS pipe).
// Result: lane 31 = sum(lanes 0..31), lane 63 = sum(lanes 32..63).
__device__ __forceinline__ float dpp_sum32(float v){
    int x;
    x = __builtin_amdgcn_update_dpp(0, __builtin_bit_cast(int, v), 0x111, 0xf, 0xf, true); v += __builtin_bit_cast(float, x);
    x = __builtin_amdgcn_update_dpp(0, __builtin_bit_cast(int, v), 0x112, 0xf, 0xf, true); v += __builtin_bit_cast(float, x);
    x = __builtin_amdgcn_update_dpp(0, __builtin_bit_cast(int, v), 0x114, 0xf, 0xf, true); v += __builtin_bit_cast(float, x);
    x = __builtin_amdgcn_update_dpp(0, __builtin_bit_cast(int, v), 0x118, 0xf, 0xf, true); v += __builtin_bit_cast(float, x);
    x = __builtin_amdgcn_update_dpp(0, __builtin_bit_cast(int, v), 0x142, 0xf, 0xf, true); v += __builtin_bit_cast(float, x);
    return v;
}

// One GRU direction for one batch element per 32-lane group.
// lane i (<24) owns hidden unit i; lanes 24..31 carry zero weights (h stays 0).
// h lives in LDS as f16[32] per group; all cross-lane exchange is wave-synchronous.
template<bool FWD>
__device__ __forceinline__ void run_dir(
    const float* xrow,            // LDS: this batch element's x, (TT,2) f32
    uint* hrow,                   // LDS: 16 uints = 32 f16, h state
    float* prow,                  // LDS: PSTR floats, per-t projection partials
    const float* __restrict__ w_ih, const float* __restrict__ w_hh,
    const float* __restrict__ b_ih, const float* __restrict__ b_hh,
    const float* __restrict__ w_out, int lane)
{
    const int   ii  = (lane < HID) ? lane : 0;
    const float msk = (lane < HID) ? 1.0f : 0.0f;

    // Pre-scales: r,z rows by -log2(e) -> sigma(a) = 1/(1+2^A).
    // n rows (hh and ih parts) by 2*log2(e) -> tanh(y) = 1 - 2/(1+2^Y).
    const float SRZ = -1.4426950408889634f * msk;
    const float SN  =  2.8853900817779268f * msk;

    const float4* r4 = reinterpret_cast<const float4*>(w_hh + ii * HID);
    const float4* z4 = reinterpret_cast<const float4*>(w_hh + (HID + ii) * HID);
    const float4* n4 = reinterpret_cast<const float4*>(w_hh + (2 * HID + ii) * HID);

    // 36 packed-f16 weight registers
    h2 wr0,wr1,wr2,wr3,wr4,wr5,wr6,wr7,wr8,wr9,wr10,wr11;
    h2 wz0,wz1,wz2,wz3,wz4,wz5,wz6,wz7,wz8,wz9,wz10,wz11;
    h2 wn0,wn1,wn2,wn3,wn4,wn5,wn6,wn7,wn8,wn9,wn10,wn11;
#define LDW(d0, d1, Q, S) { float4 q_ = (Q); d0 = pk(q_.x*(S), q_.y*(S)); d1 = pk(q_.z*(S), q_.w*(S)); OPAQUE(d0); OPAQUE(d1); }
    LDW(wr0, wr1, r4[0], SRZ) LDW(wr2, wr3, r4[1], SRZ) LDW(wr4, wr5, r4[2], SRZ)
    LDW(wr6, wr7, r4[3], SRZ) LDW(wr8, wr9, r4[4], SRZ) LDW(wr10,wr11,r4[5], SRZ)
    LDW(wz0, wz1, z4[0], SRZ) LDW(wz2, wz3, z4[1], SRZ) LDW(wz4, wz5, z4[2], SRZ)
    LDW(wz6, wz7, z4[3], SRZ) LDW(wz8, wz9, z4[4], SRZ) LDW(wz10,wz11,z4[5], SRZ)
    LDW(wn0, wn1, n4[0], SN ) LDW(wn2, wn3, n4[1], SN ) LDW(wn4, wn5, n4[2], SN )
    LDW(wn6, wn7, n4[3], SN ) LDW(wn8, wn9, n4[4], SN ) LDW(wn10,wn11,n4[5], SN )
#undef LDW

    h2 wxr = pk(w_ih[2*ii] * SRZ,          w_ih[2*ii+1] * SRZ);
    h2 wxz = pk(w_ih[2*(HID+ii)] * SRZ,    w_ih[2*(HID+ii)+1] * SRZ);
    h2 wxn = pk(w_ih[2*(2*HID+ii)] * SN,   w_ih[2*(2*HID+ii)+1] * SN);
    float br  = (b_ih[ii]       + b_hh[ii])       * SRZ;
    float bz  = (b_ih[HID+ii]   + b_hh[HID+ii])   * SRZ;
    float bnh =  b_hh[2*HID+ii] * SN;
    float bni =  b_ih[2*HID+ii] * SN;
    float pw  =  w_out[(FWD ? 0 : HID) + ii] * msk;
    OPAQUE(wxr); OPAQUE(wxz); OPAQUE(wxn);

    float hself = 0.0f;
    reinterpret_cast<_Float16*>(hrow)[lane] = (_Float16)0.0f;  // zero 32 f16 (incl pad)
    asm volatile("" ::: "memory");

    const uint4* h16 = reinterpret_cast<const uint4*>(hrow);
    int t = FWD ? 0 : (TT - 1);
    const int steps = FWD ? KOUT : TT;   // fwd t>=256 never reaches the sliced output

    #pragma unroll 1
    for (int s = 0; s < steps; ++s){
        const float2 xv = *reinterpret_cast<const float2*>(xrow + 2 * t);
        const h2 xp = __builtin_bit_cast(h2, __builtin_amdgcn_cvt_pkrtz(xv.x, xv.y));

        float ar = br, az = bz, an = bnh, ai = bni;
        uint4 q; h2 hp;
#define D3(u, WR, WZ, WN) { hp = __builtin_bit_cast(h2, (u)); DOT2(ar, hp, WR); DOT2(az, hp, WZ); DOT2(an, hp, WN); }
        q = h16[0];
        D3(q.x, wr0, wz0, wn0) D3(q.y, wr1, wz1, wn1) D3(q.z, wr2, wz2, wn2) D3(q.w, wr3, wz3, wn3)
        q = h16[1];
        D3(q.x, wr4, wz4, wn4) D3(q.y, wr5, wz5, wn5) D3(q.z, wr6, wz6, wn6) D3(q.w, wr7, wz7, wn7)
        q = h16[2];
        D3(q.x, wr8, wz8, wn8) D3(q.y, wr9, wz9, wn9) D3(q.z, wr10,wz10,wn10) D3(q.w, wr11,wz11,wn11)
#undef D3
        DOT2(ar, xp, wxr);
        DOT2(az, xp, wxz);
        DOT2(ai, xp, wxn);

        float r = sig2(ar);
        float z = sig2(az);
        float Y = fmaf(r, an, ai);
        float n = fmaf(-2.0f, __builtin_amdgcn_rcpf(1.0f + __builtin_amdgcn_exp2f(Y)), 1.0f);
        float hnew = fmaf(z, hself - n, n);   // (1-z)*n + z*h
        hself = hnew;
        reinterpret_cast<_Float16*>(hrow)[lane] = (_Float16)hnew;

        // output projection: VALU-only DPP reduction (no LDS pipe, no bpermute)
        float pv = dpp_sum32(hnew * pw);
        if (FWD){
            if (lane == 31) prow[t] = pv;
        } else {
            if (lane == 31 && t < KOUT) prow[t] += pv;
        }
        asm volatile("" ::: "memory");   // order hrow write vs next step's reads
        t += FWD ? 1 : -1;
    }
}

__global__
__attribute__((amdgpu_flat_work_group_size(256, 256)))
__attribute__((amdgpu_waves_per_eu(4, 4)))
NUMVGPR_ATTR
void birnn_kernel(
    const float* __restrict__ x,
    const float* __restrict__ w_ih_f, const float* __restrict__ w_hh_f,
    const float* __restrict__ b_ih_f, const float* __restrict__ b_hh_f,
    const float* __restrict__ w_ih_b, const float* __restrict__ w_hh_b,
    const float* __restrict__ b_ih_b, const float* __restrict__ b_hh_b,
    const float* __restrict__ w_out,  const float* __restrict__ b_out,
    float* __restrict__ out)
{
    __shared__ __align__(16) float4 xs4[BPB * TT * 2 / 4];   // 16768 B staged x
    __shared__ __align__(16) uint   hsm[BPB][16];            //   512 B h state (f16)
    __shared__ float  psm[BPB][PSTR];                        //  8320 B projection partials

    const int tid  = threadIdx.x;
    const int g    = tid >> 5;
    const int lane = tid & 31;
    const int b0   = blockIdx.x * BPB;

    // stage this block's 8 batch rows of x (contiguous 4192 floats), coalesced
    const float4* xg = reinterpret_cast<const float4*>(x + (size_t)b0 * (TT * 2));
    for (int i = tid; i < BPB * TT * 2 / 4; i += 256) xs4[i] = xg[i];
    __syncthreads();

    const float* xrow = reinterpret_cast<const float*>(xs4) + g * (TT * 2);
    run_dir<true >(xrow, hsm[g], psm[g], w_ih_f, w_hh_f, b_ih_f, b_hh_f, w_out, lane);
    run_dir<false>(xrow, hsm[g], psm[g], w_ih_b, w_hh_b, b_ih_b, b_hh_b, w_out, lane);
    __syncthreads();

    const float bo = b_out[0];
    for (int i = tid; i < BPB * KOUT; i += 256){
        int bl = i >> 8, t = i & 255;
        out[(size_t)(b0 + bl) * KOUT + t] = psm[bl][t] + bo;
    }
}

extern "C" void kernel_launch(void* const* d_in, const int* in_sizes, int n_in,
                              void* d_out, int out_size, void* d_ws, size_t ws_size,
                              hipStream_t stream)
{
    const float* x      = (const float*)d_in[0];
    const float* w_ih_f = (const float*)d_in[1];
    const float* w_hh_f = (const float*)d_in[2];
    const float* b_ih_f = (const float*)d_in[3];
    const float* b_hh_f = (const float*)d_in[4];
    const float* w_ih_b = (const float*)d_in[5];
    const float* w_hh_b = (const float*)d_in[6];
    const float* b_ih_b = (const float*)d_in[7];
    const float* b_hh_b = (const float*)d_in[8];
    const float* w_out  = (const float*)d_in[9];
    const float* b_out  = (const float*)d_in[10];
    float* out = (float*)d_out;

    birnn_kernel<<<dim3(8192 / BPB), dim3(256), 0, stream>>>(
        x, w_ih_f, w_hh_f, b_ih_f, b_hh_f,
        w_ih_b, w_hh_b, b_ih_b, b_hh_b, w_out, b_out, out);
}

// Round 13
// 394.459 us; speedup vs baseline: 1.2025x; 1.0001x over previous
//
#include <hip/hip_runtime.h>

#define HID  24
#define TT   262
#define KOUT 256

typedef _Float16 h2 __attribute__((ext_vector_type(2)));

// f32 += dot2(2xf16, 2xf16) — VOP3P V_DOT2_F32_F16
#define DOT2(acc, a, b) asm("v_dot2_f32_f16 %0, %1, %2, %0" : "+v"(acc) : "v"(a), "v"(b))
// Opaque def: pins value in a VGPR, blocks rematerialization of its def chain.
#define OPAQUE(x)       asm volatile("" : "+v"(x))

__device__ __forceinline__ float sig2(float x){   // sigma of pre-scaled arg: 1/(1+2^x)
    return __builtin_amdgcn_rcpf(1.0f + __builtin_amdgcn_exp2f(x));
}
__device__ __forceinline__ h2 pk(float a, float b){   // RTN f32->f16 pack
    h2 r; r.x = (_Float16)a; r.y = (_Float16)b; return r;
}

// Sum within each 32-lane half of the wave using DPP (pure VALU, no LDS pipe).
// Result: lane 31 = sum(lanes 0..31), lane 63 = sum(lanes 32..63).
__device__ __forceinline__ float dpp_sum32(float v){
    int x;
    x = __builtin_amdgcn_update_dpp(0, __builtin_bit_cast(int, v), 0x111, 0xf, 0xf, true); v += __builtin_bit_cast(float, x);
    x = __builtin_amdgcn_update_dpp(0, __builtin_bit_cast(int, v), 0x112, 0xf, 0xf, true); v += __builtin_bit_cast(float, x);
    x = __builtin_amdgcn_update_dpp(0, __builtin_bit_cast(int, v), 0x114, 0xf, 0xf, true); v += __builtin_bit_cast(float, x);
    x = __builtin_amdgcn_update_dpp(0, __builtin_bit_cast(int, v), 0x118, 0xf, 0xf, true); v += __builtin_bit_cast(float, x);
    x = __builtin_amdgcn_update_dpp(0, __builtin_bit_cast(int, v), 0x142, 0xf, 0xf, true); v += __builtin_bit_cast(float, x);
    return v;
}

// One batch element per 64-lane wave. Lanes 0-31: FORWARD scan; lanes 32-63:
// BACKWARD scan (independent recurrences, direction picked per-lane via
// selected pointers). Unit lane = tid&31; lanes 24-31/56-63 carry zero
// weights. h state: f16[64] in LDS (fwd row = bytes 0..63, bwd = 64..127).
// Numerics are byte-identical per direction to the proven sequential kernel.
__global__ __launch_bounds__(64)
__attribute__((amdgpu_waves_per_eu(8)))
void birnn_kernel(
    const float* __restrict__ x,
    const float* __restrict__ w_ih_f, const float* __restrict__ w_hh_f,
    const float* __restrict__ b_ih_f, const float* __restrict__ b_hh_f,
    const float* __restrict__ w_ih_b, const float* __restrict__ w_hh_b,
    const float* __restrict__ b_ih_b, const float* __restrict__ b_hh_b,
    const float* __restrict__ w_out,  const float* __restrict__ b_out,
    float* __restrict__ out)
{
    __shared__ __align__(16) float4 xs4[(TT * 2) / 4];  // 2096 B: this element's x
    __shared__ __align__(16) uint   hh[32];             //  128 B: h f16, both dirs
    __shared__ float psf[KOUT];                         // 1024 B fwd partials
    __shared__ float psb[KOUT];                         // 1024 B bwd partials

    const int tid  = threadIdx.x;
    const int half = tid >> 5;        // 0 = forward, 1 = backward
    const int ul   = tid & 31;        // unit lane within direction
    const int e    = blockIdx.x;

    // stage this element's x row (524 floats), coalesced
    const float4* xg = reinterpret_cast<const float4*>(x + (size_t)e * (TT * 2));
    for (int i = tid; i < (TT * 2) / 4; i += 64) xs4[i] = xg[i];
    __syncthreads();
    const float* xlds = reinterpret_cast<const float*>(xs4);

    // per-lane direction-selected parameter pointers
    const float* w_ih = half ? w_ih_b : w_ih_f;
    const float* w_hh = half ? w_hh_b : w_hh_f;
    const float* b_ih = half ? b_ih_b : b_ih_f;
    const float* b_hh = half ? b_hh_b : b_hh_f;

    const int   ii  = (ul < HID) ? ul : 0;
    const float msk = (ul < HID) ? 1.0f : 0.0f;

    // Pre-scales: r,z rows by -log2(e) -> sigma(a) = 1/(1+2^A);
    // n rows by 2*log2(e) -> tanh(y) = 1 - 2/(1+2^Y).
    const float SRZ = -1.4426950408889634f * msk;
    const float SN  =  2.8853900817779268f * msk;

    const float4* r4 = reinterpret_cast<const float4*>(w_hh + ii * HID);
    const float4* z4 = reinterpret_cast<const float4*>(w_hh + (HID + ii) * HID);
    const float4* n4 = reinterpret_cast<const float4*>(w_hh + (2 * HID + ii) * HID);

    // 36 packed-f16 weight registers (shared register names, per-lane values)
    h2 wr0,wr1,wr2,wr3,wr4,wr5,wr6,wr7,wr8,wr9,wr10,wr11;
    h2 wz0,wz1,wz2,wz3,wz4,wz5,wz6,wz7,wz8,wz9,wz10,wz11;
    h2 wn0,wn1,wn2,wn3,wn4,wn5,wn6,wn7,wn8,wn9,wn10,wn11;
#define LDW(d0, d1, Q, S) { float4 q_ = (Q); d0 = pk(q_.x*(S), q_.y*(S)); d1 = pk(q_.z*(S), q_.w*(S)); OPAQUE(d0); OPAQUE(d1); }
    LDW(wr0, wr1, r4[0], SRZ) LDW(wr2, wr3, r4[1], SRZ) LDW(wr4, wr5, r4[2], SRZ)
    LDW(wr6, wr7, r4[3], SRZ) LDW(wr8, wr9, r4[4], SRZ) LDW(wr10,wr11,r4[5], SRZ)
    LDW(wz0, wz1, z4[0], SRZ) LDW(wz2, wz3, z4[1], SRZ) LDW(wz4, wz5, z4[2], SRZ)
    LDW(wz6, wz7, z4[3], SRZ) LDW(wz8, wz9, z4[4], SRZ) LDW(wz10,wz11,z4[5], SRZ)
    LDW(wn0, wn1, n4[0], SN ) LDW(wn2, wn3, n4[1], SN ) LDW(wn4, wn5, n4[2], SN )
    LDW(wn6, wn7, n4[3], SN ) LDW(wn8, wn9, n4[4], SN ) LDW(wn10,wn11,n4[5], SN )
#undef LDW

    h2 wxr = pk(w_ih[2*ii] * SRZ,          w_ih[2*ii+1] * SRZ);
    h2 wxz = pk(w_ih[2*(HID+ii)] * SRZ,    w_ih[2*(HID+ii)+1] * SRZ);
    h2 wxn = pk(w_ih[2*(2*HID+ii)] * SN,   w_ih[2*(2*HID+ii)+1] * SN);
    float br  = (b_ih[ii]       + b_hh[ii])       * SRZ;
    float bz  = (b_ih[HID+ii]   + b_hh[HID+ii])   * SRZ;
    float bnh =  b_hh[2*HID+ii] * SN;
    float bni =  b_ih[2*HID+ii] * SN;
    float pw  =  w_out[(half ? HID : 0) + ii] * msk;
    OPAQUE(wxr); OPAQUE(wxz); OPAQUE(wxn);

    float* pdst = half ? psb : psf;

    float hself = 0.0f;
    reinterpret_cast<_Float16*>(hh)[tid] = (_Float16)0.0f;   // zero both h rows
    asm volatile("" ::: "memory");

    // fwd half reads uint4 0..2, bwd half 4..6 (per-lane base)
    const uint4* h16 = reinterpret_cast<const uint4*>(hh) + (half << 2);

    #pragma unroll 1
    for (int s = 0; s < TT; ++s){
        const int tcur = half ? (TT - 1 - s) : s;   // per-lane time index
        const float2 xv = *reinterpret_cast<const float2*>(xlds + 2 * tcur);
        const h2 xp = __builtin_bit_cast(h2, __builtin_amdgcn_cvt_pkrtz(xv.x, xv.y));

        float ar = br, az = bz, an = bnh, ai = bni;
        uint4 q; h2 hp;
#define D3(u, WR, WZ, WN) { hp = __builtin_bit_cast(h2, (u)); DOT2(ar, hp, WR); DOT2(az, hp, WZ); DOT2(an, hp, WN); }
        q = h16[0];
        D3(q.x, wr0, wz0, wn0) D3(q.y, wr1, wz1, wn1) D3(q.z, wr2, wz2, wn2) D3(q.w, wr3, wz3, wn3)
        q = h16[1];
        D3(q.x, wr4, wz4, wn4) D3(q.y, wr5, wz5, wn5) D3(q.z, wr6, wz6, wn6) D3(q.w, wr7, wz7, wn7)
        q = h16[2];
        D3(q.x, wr8, wz8, wn8) D3(q.y, wr9, wz9, wn9) D3(q.z, wr10,wz10,wn10) D3(q.w, wr11,wz11,wn11)
#undef D3
        DOT2(ar, xp, wxr);
        DOT2(az, xp, wxz);
        DOT2(ai, xp, wxn);

        float r = sig2(ar);
        float z = sig2(az);
        float Y = fmaf(r, an, ai);
        float n = fmaf(-2.0f, __builtin_amdgcn_rcpf(1.0f + __builtin_amdgcn_exp2f(Y)), 1.0f);
        float hnew = fmaf(z, hself - n, n);   // (1-z)*n + z*h
        hself = hnew;
        reinterpret_cast<_Float16*>(hh)[tid] = (_Float16)hnew;

        // output projection: per-half DPP reduction; lanes 31/63 hold the sums
        float pv = dpp_sum32(hnew * pw);
        if (ul == 31 && tcur < KOUT) pdst[tcur] = pv;
        asm volatile("" ::: "memory");   // order h write vs next step's reads
    }
    __syncthreads();

    const float bo = b_out[0];
    for (int k = tid; k < KOUT; k += 64)
        out[(size_t)e * KOUT + k] = psf[k] + psb[k] + bo;
}

extern "C" void kernel_launch(void* const* d_in, const int* in_sizes, int n_in,
                              void* d_out, int out_size, void* d_ws, size_t ws_size,
                              hipStream_t stream)
{
    const float* x      = (const float*)d_in[0];
    const float* w_ih_f = (const float*)d_in[1];
    const float* w_hh_f = (const float*)d_in[2];
    const float* b_ih_f = (const float*)d_in[3];
    const float* b_hh_f = (const float*)d_in[4];
    const float* w_ih_b = (const float*)d_in[5];
    const float* w_hh_b = (const float*)d_in[6];
    const float* b_ih_b = (const float*)d_in[7];
    const float* b_hh_b = (const float*)d_in[8];
    const float* w_out  = (const float*)d_in[9];
    const float* b_out  = (const float*)d_in[10];
    float* out = (float*)d_out;

    birnn_kernel<<<dim3(8192), dim3(64), 0, stream>>>(
        x, w_ih_f, w_hh_f, b_ih_f, b_hh_f,
        w_ih_b, w_hh_b, b_ih_b, b_hh_b, w_out, b_out, out);
}